// Round 8
// baseline (611.075 us; speedup 1.0000x reference)
//
#include <hip/hip_runtime.h>

static constexpr int D        = 64;   // N_FACTORS
static constexpr int N_LAYERS = 3;
static constexpr int SH2      = 8;    // coarse bucket = 256 rows
static constexpr int T1       = 4096; // edges per pass-1 tile
static constexpr int CAP      = 8896; // fixed bucket capacity: mean 8192, sigma~90 -> +7.8 sigma
static constexpr int NINIT    = 448;  // init blocks fused into part1 grid

// Edge encoding (final, SpMM-ready): u32 = (col << 14) | q14(val)
//   col < 2^18, q14 = round(val*16384) clamped to 16383 (val in [0,1)).
//   x-index = ((E>>11) & ~7) | ch ;  val = (float)(E & 0x3FFF) * (1/16384)
//   The 1/16384 scale is hoisted out of the edge loop (linear in val).

// ---------------- bf16 helpers (RNE pack, exact unpack) ----------------
__device__ inline unsigned pack_bf2(float a, float b) {
    unsigned ua = __float_as_uint(a); ua = (ua + 0x7FFFu + ((ua >> 16) & 1u)) >> 16;
    unsigned ub = __float_as_uint(b); ub = (ub + 0x7FFFu + ((ub >> 16) & 1u)) >> 16;
    return ua | (ub << 16);
}
__device__ inline float blo(unsigned u) { return __uint_as_float(u << 16); }
__device__ inline float bhi(unsigned u) { return __uint_as_float(u & 0xFFFF0000u); }

// ===========================================================================
// Pass 1 (R8 rewrite, fused with init): NO LDS edge staging. Per tile:
//   Pass A: read row[] only -> per-bucket hist (LDS, 9 KB total).
//   Reserve: gcur[b] = b*CAP + atomicAdd(&gcnt[b], hist[b]) (clamped -> no
//            OOB even on tail-probability overflow).
//   Pass B: re-read row/col/val, encode g1=(col<<14)|q14(val), scatter
//           g1/lr to pos = gcur[b] + atomicAdd(&bincur[b],1).
// Drops the scan/perm/binstart machinery and 36 KB of LDS: occupancy goes
// 2-3 blocks/CU -> 8 blocks/CU, hiding the global-load + scatter latency.
// Bucket-internal order becomes arbitrary -- part2/SpMM don't require it.
// Interleaved blocks (odd bid < 2*nInit) run the bf16 init stream instead.
// ===========================================================================
__global__ __launch_bounds__(256) void k_part1f(const int* __restrict__ row,
                                                const int* __restrict__ col,
                                                const float* __restrict__ val,
                                                int* __restrict__ gcnt,
                                                unsigned* __restrict__ g1,
                                                unsigned char* __restrict__ lr,
                                                int nnz, int NB2, int nInit,
                                                const float4* __restrict__ ue,
                                                const float4* __restrict__ ie,
                                                uint4* __restrict__ cur,
                                                int nUser8, int nTot8) {
    __shared__ int hist[768];                 // >= NB2
    __shared__ int gcur[768];
    __shared__ int bincur[768];

    int tid = threadIdx.x;
    int bid = blockIdx.x;
    int tile;
    if (bid < 2 * nInit) {
        if (bid & 1) {
            // ---- init path: buf0(bf16) = emb0 (LAST merge reads this) ----
            int stride = nInit * 256;
            for (int i = (bid >> 1) * 256 + tid; i < nTot8; i += stride) {
                float4 f0, f1;
                if (i < nUser8) { f0 = ue[2 * i];              f1 = ue[2 * i + 1]; }
                else            { int j = i - nUser8; f0 = ie[2 * j]; f1 = ie[2 * j + 1]; }
                cur[i] = make_uint4(pack_bf2(f0.x, f0.y), pack_bf2(f0.z, f0.w),
                                    pack_bf2(f1.x, f1.y), pack_bf2(f1.z, f1.w));
            }
            return;
        }
        tile = bid >> 1;
    } else {
        tile = bid - nInit;
    }

    int base = tile * T1;
    int n    = nnz - base; if (n > T1) n = T1;

    for (int b = tid; b < NB2; b += 256) { hist[b] = 0; bincur[b] = 0; }
    __syncthreads();

    // Pass A: bucket histogram from row[] only
    for (int i = tid; i < n; i += 256)
        atomicAdd(&hist[row[base + i] >> SH2], 1);
    __syncthreads();

    // reserve global ranges inside fixed-capacity buckets (clamped: no OOB ever)
    for (int b = tid; b < NB2; b += 256) {
        int c = hist[b];
        if (c) {
            int o = atomicAdd(&gcnt[b], c);
            int lim = CAP - c;
            if (o > lim) o = lim;            // tail-probability overflow: overwrite, don't fault
            gcur[b] = b * CAP + o;
        }
    }
    __syncthreads();

    // Pass B: encode + direct scatter (arbitrary order within bucket)
    for (int i = tid; i < n; i += 256) {
        int e = base + i;
        int r = row[e];
        int q = (int)(val[e] * 16384.f + 0.5f);
        if (q > 16383) q = 16383;
        unsigned enc = ((unsigned)col[e] << 14) | (unsigned)q;
        int b = r >> SH2;
        int pos = gcur[b] + atomicAdd(&bincur[b], 1);
        g1[pos] = enc;
        lr[pos] = (unsigned char)(r & ((1 << SH2) - 1));
    }
}

// ===========================================================================
// Pass 2: one 512-thread block per coarse bucket, NO LDS staging (3 KB LDS
// -> high wave occupancy). Pass A reads the lr window -> 256-row hist;
// scan -> per-row (start,end) rowptr; Pass B re-reads lr+g1 (window is
// L2-hot) and scatters into the SEPARATE ecv buffer (no aliasing).
// ===========================================================================
__global__ __launch_bounds__(512) void k_part2(const int* __restrict__ gcnt,
                                               const unsigned* __restrict__ g1,
                                               const unsigned char* __restrict__ lr,
                                               unsigned* __restrict__ ecv,
                                               int2* __restrict__ rowptr2) {
    __shared__ int hist[256];
    __shared__ int cur[256];
    __shared__ int ssum[256];
    int b   = blockIdx.x;
    int tid = threadIdx.x;
    int lo  = b * CAP;
    int cnt = gcnt[b];
    if (cnt > CAP) cnt = CAP;                 // defensive: stay inside the window

    if (tid < 256) hist[tid] = 0;
    __syncthreads();
    for (int i = tid; i < cnt; i += 512)
        atomicAdd(&hist[lr[lo + i]], 1);
    __syncthreads();

    if (tid < 256) ssum[tid] = hist[tid];
    __syncthreads();
    for (int off = 1; off < 256; off <<= 1) {
        int v = 0;
        if (tid < 256 && tid >= off) v = ssum[tid - off];
        __syncthreads();
        if (tid < 256) ssum[tid] += v;
        __syncthreads();
    }
    if (tid < 256) {
        int h    = hist[tid];
        int excl = ssum[tid] - h;
        cur[tid] = excl;
        rowptr2[(b << SH2) + tid] = make_int2(lo + excl, lo + excl + h);
    }
    __syncthreads();

    for (int i = tid; i < cnt; i += 512) {
        int r = lr[lo + i];
        int p = atomicAdd(&cur[r], 1);
        ecv[lo + p] = g1[lo + i];             // scatter lands in L2-resident window
    }
}

// ===========================================================================
// SpMM (bf16 x, u32 edges): one wave per row. lane = grp*8 + ch; 8 edge
// slots per wave, lane gathers 16 B (= 8 bf16) of x[col]. fp32 accumulate.
// 4-deep unrolled main loop + 2-edge + 1-edge remainder (R7; at the
// ~3.5 TB/s random-gather service-rate equilibrium -- do not touch).
// 1/16384 val-scale hoisted to the per-row epilogue. shfl_xor(8,16,32).
// Defer-acc: MID layers write ONLY y. LAST reconstructs
// acc = 0.25*(emb0_bf16 + y1 + y2 + s3); y2 == this layer's x buffer.
// ===========================================================================
template <bool LAST>
__global__ void k_spmm_bf(const int2* __restrict__ rowptr2,
                          const unsigned* __restrict__ ecv,
                          const uint4* __restrict__ x, uint4* __restrict__ y,
                          float* __restrict__ acc,
                          const uint4* __restrict__ e0b,
                          const uint4* __restrict__ y1,
                          int N) {
    int wid = (blockIdx.x * blockDim.x + threadIdx.x) >> 6;
    if (wid >= N) return;
    int lane = threadIdx.x & 63;
    int grp  = lane >> 3;          // edge slot within wave [0,8)
    unsigned ch = (unsigned)(lane & 7);   // 16B chunk of the 128B bf16 row
    int2 rp = rowptr2[wid];
    int e0 = rp.x;
    int e1 = rp.y;
    float s0 = 0.f, s1 = 0.f, s2 = 0.f, s3 = 0.f;
    float s4 = 0.f, s5 = 0.f, s6 = 0.f, s7 = 0.f;
    int e = e0 + grp;
    // ---- 4-deep main loop: 4 outstanding gathers per lane ----
    for (; e + 24 < e1; e += 32) {
        unsigned A0 = ecv[e];
        unsigned A1 = ecv[e + 8];
        unsigned A2 = ecv[e + 16];
        unsigned A3 = ecv[e + 24];
        uint4 x0 = x[((A0 >> 11) & ~7u) | ch];
        uint4 x1 = x[((A1 >> 11) & ~7u) | ch];
        uint4 x2 = x[((A2 >> 11) & ~7u) | ch];
        uint4 x3 = x[((A3 >> 11) & ~7u) | ch];
        float v0 = (float)(A0 & 0x3FFFu);
        float v1 = (float)(A1 & 0x3FFFu);
        float v2 = (float)(A2 & 0x3FFFu);
        float v3 = (float)(A3 & 0x3FFFu);
        s0 += v0 * blo(x0.x) + v1 * blo(x1.x) + v2 * blo(x2.x) + v3 * blo(x3.x);
        s1 += v0 * bhi(x0.x) + v1 * bhi(x1.x) + v2 * bhi(x2.x) + v3 * bhi(x3.x);
        s2 += v0 * blo(x0.y) + v1 * blo(x1.y) + v2 * blo(x2.y) + v3 * blo(x3.y);
        s3 += v0 * bhi(x0.y) + v1 * bhi(x1.y) + v2 * bhi(x2.y) + v3 * bhi(x3.y);
        s4 += v0 * blo(x0.z) + v1 * blo(x1.z) + v2 * blo(x2.z) + v3 * blo(x3.z);
        s5 += v0 * bhi(x0.z) + v1 * bhi(x1.z) + v2 * bhi(x2.z) + v3 * bhi(x3.z);
        s6 += v0 * blo(x0.w) + v1 * blo(x1.w) + v2 * blo(x2.w) + v3 * blo(x3.w);
        s7 += v0 * bhi(x0.w) + v1 * bhi(x1.w) + v2 * bhi(x2.w) + v3 * bhi(x3.w);
    }
    // ---- 2-edge step ----
    for (; e + 8 < e1; e += 16) {
        unsigned A = ecv[e];
        unsigned C = ecv[e + 8];
        uint4 xa = x[((A >> 11) & ~7u) | ch];
        uint4 xc = x[((C >> 11) & ~7u) | ch];
        float va = (float)(A & 0x3FFFu);
        float vc = (float)(C & 0x3FFFu);
        s0 += va * blo(xa.x) + vc * blo(xc.x);
        s1 += va * bhi(xa.x) + vc * bhi(xc.x);
        s2 += va * blo(xa.y) + vc * blo(xc.y);
        s3 += va * bhi(xa.y) + vc * bhi(xc.y);
        s4 += va * blo(xa.z) + vc * blo(xc.z);
        s5 += va * bhi(xa.z) + vc * bhi(xc.z);
        s6 += va * blo(xa.w) + vc * blo(xc.w);
        s7 += va * bhi(xa.w) + vc * bhi(xc.w);
    }
    if (e < e1) {
        unsigned A = ecv[e];
        uint4 xa = x[((A >> 11) & ~7u) | ch];
        float va = (float)(A & 0x3FFFu);
        s0 += va * blo(xa.x); s1 += va * bhi(xa.x);
        s2 += va * blo(xa.y); s3 += va * bhi(xa.y);
        s4 += va * blo(xa.z); s5 += va * bhi(xa.z);
        s6 += va * blo(xa.w); s7 += va * bhi(xa.w);
    }
    #pragma unroll
    for (int m = 8; m <= 32; m <<= 1) {
        s0 += __shfl_xor(s0, m); s1 += __shfl_xor(s1, m);
        s2 += __shfl_xor(s2, m); s3 += __shfl_xor(s3, m);
        s4 += __shfl_xor(s4, m); s5 += __shfl_xor(s5, m);
        s6 += __shfl_xor(s6, m); s7 += __shfl_xor(s7, m);
    }
    if (grp == 0) {
        if (!LAST) {
            // mid layer: write y only -- zero acc traffic
            const float SC = 1.f / 16384.f;
            y[(size_t)wid * 8 + ch] =
                make_uint4(pack_bf2(s0 * SC, s1 * SC), pack_bf2(s2 * SC, s3 * SC),
                           pack_bf2(s4 * SC, s5 * SC), pack_bf2(s6 * SC, s7 * SC));
        } else {
            // final merge: acc = 0.25*(emb0 + y1 + y2) + s*0.25/16384
            const float SC25 = 0.25f / 16384.f;
            size_t ro = (size_t)wid * 8 + ch;
            uint4 u0 = e0b[ro];
            uint4 u1 = y1[ro];
            uint4 u2 = x [ro];
            float4 a0, a1;
            a0.x = (blo(u0.x) + blo(u1.x) + blo(u2.x)) * 0.25f + s0 * SC25;
            a0.y = (bhi(u0.x) + bhi(u1.x) + bhi(u2.x)) * 0.25f + s1 * SC25;
            a0.z = (blo(u0.y) + blo(u1.y) + blo(u2.y)) * 0.25f + s2 * SC25;
            a0.w = (bhi(u0.y) + bhi(u1.y) + bhi(u2.y)) * 0.25f + s3 * SC25;
            a1.x = (blo(u0.z) + blo(u1.z) + blo(u2.z)) * 0.25f + s4 * SC25;
            a1.y = (bhi(u0.z) + bhi(u1.z) + bhi(u2.z)) * 0.25f + s5 * SC25;
            a1.z = (blo(u0.w) + blo(u1.w) + blo(u2.w)) * 0.25f + s6 * SC25;
            a1.w = (bhi(u0.w) + bhi(u1.w) + bhi(u2.w)) * 0.25f + s7 * SC25;
            size_t o = ((size_t)wid << 6) + (ch << 3);
            *(float4*)(acc + o)     = a0;
            *(float4*)(acc + o + 4) = a1;
        }
    }
}

// ===========================================================================
// Fallback (atomic path, fp32) if ws is too small
// ===========================================================================
__global__ void k_init(const float4* __restrict__ ue, const float4* __restrict__ ie,
                       float4* __restrict__ cur, float4* __restrict__ acc,
                       int nUser4, int nTot4) {
    int stride = gridDim.x * blockDim.x;
    for (int i = blockIdx.x * blockDim.x + threadIdx.x; i < nTot4; i += stride) {
        float4 v = (i < nUser4) ? ue[i] : ie[i - nUser4];
        cur[i] = v;
        acc[i] = v;
    }
}

__global__ void k_spmm_atomic(const int* __restrict__ row, const int* __restrict__ col,
                              const float* __restrict__ val, const float* __restrict__ x,
                              float* __restrict__ y, int nnz) {
    long long total  = (long long)nnz * 16;
    long long stride = (long long)gridDim.x * blockDim.x;
    for (long long idx = (long long)blockIdx.x * blockDim.x + threadIdx.x;
         idx < total; idx += stride) {
        int e = (int)(idx >> 4);
        int c = (int)(idx & 15);
        int r = row[e];
        int ssrc = col[e];
        float v = val[e];
        float4 xv = *(const float4*)(x + (size_t)ssrc * D + c * 4);
        float* yp = y + (size_t)r * D + c * 4;
        atomicAdd(yp + 0, v * xv.x);
        atomicAdd(yp + 1, v * xv.y);
        atomicAdd(yp + 2, v * xv.z);
        atomicAdd(yp + 3, v * xv.w);
    }
}

__global__ void k_acc(const float4* __restrict__ nxt, float4* __restrict__ acc,
                      float scale, int n4) {
    int stride = gridDim.x * blockDim.x;
    for (int i = blockIdx.x * blockDim.x + threadIdx.x; i < n4; i += stride) {
        float4 a = acc[i];
        float4 b = nxt[i];
        a.x = (a.x + b.x) * scale;
        a.y = (a.y + b.y) * scale;
        a.z = (a.z + b.z) * scale;
        a.w = (a.w + b.w) * scale;
        acc[i] = a;
    }
}

// ===========================================================================
extern "C" void kernel_launch(void* const* d_in, const int* in_sizes, int n_in,
                              void* d_out, int out_size, void* d_ws, size_t ws_size,
                              hipStream_t stream) {
    const float* ue  = (const float*)d_in[0];
    const float* ie  = (const float*)d_in[1];
    const int*   row = (const int*)  d_in[2];
    const int*   col = (const int*)  d_in[3];
    const float* val = (const float*)d_in[4];

    const int n_users = in_sizes[0] / D;
    const int n_items = in_sizes[1] / D;
    const int nnz     = in_sizes[2];
    const int N       = n_users + n_items;
    const int NB2     = (N + (1 << SH2) - 1) >> SH2;   // 586

    float* acc = (float*)d_out;
    const size_t bf16B = (size_t)N * D * 2;    // 19.2 MB per layer buffer
    auto aup = [](size_t x) { return (x + 255) & ~(size_t)255; };

    size_t off = 0;
    uint4* buf0 = (uint4*)((char*)d_ws + off); off += aup(bf16B);   // emb0 bf16
    uint4* buf1 = (uint4*)((char*)d_ws + off); off += aup(bf16B);   // y1
    uint4* buf2 = (uint4*)((char*)d_ws + off); off += aup(bf16B);   // y2
    unsigned*      g1 = (unsigned*)     ((char*)d_ws + off); off += aup((size_t)NB2 * CAP * 4);
    unsigned char* lr = (unsigned char*)((char*)d_ws + off); off += aup((size_t)NB2 * CAP);
    unsigned*      ecv = (unsigned*)    ((char*)d_ws + off); off += aup((size_t)NB2 * CAP * 4);
    int2* rowptr2 = (int2*)((char*)d_ws + off); off += aup((size_t)(NB2 << SH2) * 8);
    int*  gcnt    = (int*) ((char*)d_ws + off); off += aup((size_t)NB2 * 4);
    const size_t needCSR = off;                 // ~106 MB (< ~117 MB proven in round-0)

    // capacity guard: mean bucket load + ~6.6 sigma must fit in CAP;
    // col must fit 18 bits for the (col<<14) packing
    bool capOK = ((size_t)nnz / NB2 + 600) <= (size_t)CAP && NB2 <= 768 &&
                 N <= (1 << 18);

    if (ws_size >= needCSR && capOK) {
        // ---- single-pass radix partition (fixed-CAP buckets) + fused init ----
        hipMemsetAsync(gcnt, 0, (size_t)NB2 * 4, stream);
        int nTiles = (nnz + T1 - 1) / T1;      // 1172
        int nInit  = NINIT < nTiles ? NINIT : nTiles;
        int nTot8  = N * 8;
        int nUser8 = n_users * 8;
        k_part1f<<<nTiles + nInit, 256, 0, stream>>>(row, col, val, gcnt, g1, lr,
                                                     nnz, NB2, nInit,
                                                     (const float4*)ue, (const float4*)ie,
                                                     buf0, nUser8, nTot8);
        k_part2<<<NB2, 512, 0, stream>>>(gcnt, g1, lr, ecv, rowptr2);

        // ---- 3 SpMM layers, defer-acc:
        //   L1: y1 = A*x0      (buf0 -> buf1), no acc traffic
        //   L2: y2 = A*y1      (buf1 -> buf2), no acc traffic
        //   L3: acc = 0.25*(emb0 + y1 + y2 + A*y2)
        int grid = (N + 3) / 4;   // one wave per row
        k_spmm_bf<false><<<grid, 256, 0, stream>>>(rowptr2, ecv, buf0, buf1,
                                                   nullptr, nullptr, nullptr, N);
        k_spmm_bf<false><<<grid, 256, 0, stream>>>(rowptr2, ecv, buf1, buf2,
                                                   nullptr, nullptr, nullptr, N);
        k_spmm_bf<true ><<<grid, 256, 0, stream>>>(rowptr2, ecv, buf2, nullptr,
                                                   acc, buf0, buf1, N);
    } else {
        // ---- fallback: atomic scatter path (fp32) ----
        const size_t denseB = (size_t)N * D * sizeof(float);
        float* fa = (float*)d_ws;
        float* fb = fa + (size_t)N * D;
        const int nTot4  = N * D / 4;
        const int nUser4 = n_users * D / 4;
        k_init<<<2048, 256, 0, stream>>>((const float4*)ue, (const float4*)ie,
                                         (float4*)fa, (float4*)acc, nUser4, nTot4);
        float* curp = fa;
        float* nxt  = fb;
        for (int l = 0; l < N_LAYERS; ++l) {
            hipMemsetAsync(nxt, 0, denseB, stream);
            k_spmm_atomic<<<8192, 256, 0, stream>>>(row, col, val, curp, nxt, nnz);
            float scale = (l == N_LAYERS - 1) ? (1.0f / (N_LAYERS + 1)) : 1.0f;
            k_acc<<<2048, 256, 0, stream>>>((const float4*)nxt, (float4*)acc, scale, nTot4);
            float* t = curp; curp = nxt; nxt = t;
        }
    }
}

// Round 9
// 470.504 us; speedup vs baseline: 1.2988x; 1.2988x over previous
//
#include <hip/hip_runtime.h>

static constexpr int D        = 64;   // N_FACTORS
static constexpr int N_LAYERS = 3;
static constexpr int SH2      = 8;    // coarse bucket = 256 rows
static constexpr int T1       = 4096; // edges per pass-1 tile
static constexpr int CAP      = 8896; // fixed bucket capacity: mean 8192, sigma~90 -> +7.8 sigma
static constexpr int NINIT    = 448;  // init blocks fused into part1 grid

// Edge encoding (final, SpMM-ready): u32 = (col << 14) | q14(val)
//   col < 2^18, q14 = round(val*16384) clamped to 16383 (val in [0,1)).
//   x-index = ((E>>11) & ~7) | ch ;  val = (float)(E & 0x3FFF) * (1/16384)
//   The 1/16384 scale is hoisted out of the edge loop (linear in val).

// ---------------- bf16 helpers (RNE pack, exact unpack) ----------------
__device__ inline unsigned pack_bf2(float a, float b) {
    unsigned ua = __float_as_uint(a); ua = (ua + 0x7FFFu + ((ua >> 16) & 1u)) >> 16;
    unsigned ub = __float_as_uint(b); ub = (ub + 0x7FFFu + ((ub >> 16) & 1u)) >> 16;
    return ua | (ub << 16);
}
__device__ inline float blo(unsigned u) { return __uint_as_float(u << 16); }
__device__ inline float bhi(unsigned u) { return __uint_as_float(u & 0xFFFF0000u); }

// ===========================================================================
// Pass 1 (R7-proven structure, fused with init): tile-LDS radix partition
// into fixed-capacity coarse buckets. Bucket b owns [b*CAP .. b*CAP+cnt).
// LDS-stage + rank + perm so global writes are COALESCED bin-sorted runs
// (R8 lesson: direct per-edge scatter = 12x write amplification, 224 us).
// Emits g1[pos] = (col<<14)|q14(val) (u32, SpMM-ready) and lr[pos] (u8).
// Reservation clamped to CAP-c: tail-probability overflow overwrites inside
// the bucket, never OOB. Scan is wave-level shfl (1 barrier, not 16).
// Interleaved blocks (odd bid < 2*nInit) run the bf16 init stream instead.
// ===========================================================================
__global__ __launch_bounds__(256) void k_part1f(const int* __restrict__ row,
                                                const int* __restrict__ col,
                                                const float* __restrict__ val,
                                                int* __restrict__ gcnt,
                                                unsigned* __restrict__ g1,
                                                unsigned char* __restrict__ lr,
                                                int nnz, int NB2, int nInit,
                                                const float4* __restrict__ ue,
                                                const float4* __restrict__ ie,
                                                uint4* __restrict__ cur,
                                                int nUser8, int nTot8) {
    __shared__ unsigned       sg1[T1];        // 16 KB
    __shared__ unsigned char  slr[T1];        // 4 KB
    __shared__ unsigned short bbin[T1];       // 8 KB
    __shared__ unsigned short perm[T1];       // 8 KB
    __shared__ int hist[768];                 // >= NB2
    __shared__ int binstart[768];
    __shared__ int gcur[768];
    __shared__ int bincur[768];
    __shared__ int wtot[4];

    int tid = threadIdx.x;
    int bid = blockIdx.x;
    int tile;
    if (bid < 2 * nInit) {
        if (bid & 1) {
            // ---- init path: buf0(bf16) = emb0 (LAST merge reads this) ----
            int stride = nInit * 256;
            for (int i = (bid >> 1) * 256 + tid; i < nTot8; i += stride) {
                float4 f0, f1;
                if (i < nUser8) { f0 = ue[2 * i];              f1 = ue[2 * i + 1]; }
                else            { int j = i - nUser8; f0 = ie[2 * j]; f1 = ie[2 * j + 1]; }
                cur[i] = make_uint4(pack_bf2(f0.x, f0.y), pack_bf2(f0.z, f0.w),
                                    pack_bf2(f1.x, f1.y), pack_bf2(f1.z, f1.w));
            }
            return;
        }
        tile = bid >> 1;
    } else {
        tile = bid - nInit;
    }

    int base = tile * T1;
    int n    = nnz - base; if (n > T1) n = T1;

    for (int b = tid; b < NB2; b += 256) { hist[b] = 0; bincur[b] = 0; }
    __syncthreads();

    // load + encode + bin + histogram
    for (int i = tid; i < n; i += 256) {
        int e = base + i;
        int r = row[e];
        int q = (int)(val[e] * 16384.f + 0.5f);
        if (q > 16383) q = 16383;
        sg1[i]  = ((unsigned)col[e] << 14) | (unsigned)q;
        slr[i]  = (unsigned char)(r & ((1 << SH2) - 1));
        int b   = r >> SH2;
        bbin[i] = (unsigned short)b;
        atomicAdd(&hist[b], 1);
    }
    __syncthreads();

    // exclusive scan of hist -> binstart: wave-level shfl scan (1 barrier)
    int per = (NB2 + 255) / 256;              // 3
    int i0  = tid * per;
    int sum = 0;
    for (int k = 0; k < per; ++k) { int i = i0 + k; if (i < NB2) sum += hist[i]; }
    int inc = sum;
    #pragma unroll
    for (int o = 1; o < 64; o <<= 1) {
        int t = __shfl_up(inc, o);
        if ((tid & 63) >= o) inc += t;
    }
    if ((tid & 63) == 63) wtot[tid >> 6] = inc;
    __syncthreads();
    int wbase = 0;
    int w = tid >> 6;
    #pragma unroll
    for (int j = 0; j < 3; ++j) if (w > j) wbase += wtot[j];
    int run = wbase + inc - sum;              // exclusive prefix across block
    for (int k = 0; k < per; ++k) {
        int i = i0 + k;
        if (i < NB2) { binstart[i] = run; run += hist[i]; }
    }
    __syncthreads();

    // reserve global ranges inside fixed-capacity buckets (clamped: no OOB ever)
    for (int b = tid; b < NB2; b += 256) {
        int c = hist[b];
        if (c) {
            int o = atomicAdd(&gcnt[b], c);
            int lim = CAP - c;
            if (o > lim) o = lim;            // tail-probability overflow: overwrite, don't fault
            gcur[b] = b * CAP + o;
        }
    }
    __syncthreads();

    // rank within tile
    for (int i = tid; i < n; i += 256) {
        int b = bbin[i];
        int rnk = binstart[b] + atomicAdd(&bincur[b], 1);
        perm[rnk] = (unsigned short)i;
    }
    __syncthreads();

    // coalesced write of bin-sorted runs (u32 + u8 streams)
    for (int j = tid; j < n; j += 256) {
        int i = perm[j];
        int b = bbin[i];
        int pos = gcur[b] + (j - binstart[b]);
        g1[pos] = sg1[i];
        lr[pos] = slr[i];
    }
}

// ===========================================================================
// Pass 2: one 512-thread block per coarse bucket, NO LDS staging (3 KB LDS
// -> high wave occupancy). Pass A reads the lr window -> 256-row hist;
// scan -> per-row (start,end) rowptr; Pass B re-reads lr+g1 (window is
// L2-hot) and scatters into the SEPARATE ecv buffer (no aliasing).
// ===========================================================================
__global__ __launch_bounds__(512) void k_part2(const int* __restrict__ gcnt,
                                               const unsigned* __restrict__ g1,
                                               const unsigned char* __restrict__ lr,
                                               unsigned* __restrict__ ecv,
                                               int2* __restrict__ rowptr2) {
    __shared__ int hist[256];
    __shared__ int cur[256];
    __shared__ int ssum[256];
    int b   = blockIdx.x;
    int tid = threadIdx.x;
    int lo  = b * CAP;
    int cnt = gcnt[b];
    if (cnt > CAP) cnt = CAP;                 // defensive: stay inside the window

    if (tid < 256) hist[tid] = 0;
    __syncthreads();
    for (int i = tid; i < cnt; i += 512)
        atomicAdd(&hist[lr[lo + i]], 1);
    __syncthreads();

    if (tid < 256) ssum[tid] = hist[tid];
    __syncthreads();
    for (int off = 1; off < 256; off <<= 1) {
        int v = 0;
        if (tid < 256 && tid >= off) v = ssum[tid - off];
        __syncthreads();
        if (tid < 256) ssum[tid] += v;
        __syncthreads();
    }
    if (tid < 256) {
        int h    = hist[tid];
        int excl = ssum[tid] - h;
        cur[tid] = excl;
        rowptr2[(b << SH2) + tid] = make_int2(lo + excl, lo + excl + h);
    }
    __syncthreads();

    for (int i = tid; i < cnt; i += 512) {
        int r = lr[lo + i];
        int p = atomicAdd(&cur[r], 1);
        ecv[lo + p] = g1[lo + i];             // scatter lands in L2-resident window
    }
}

// ===========================================================================
// SpMM (bf16 x, u32 edges): one wave per row. lane = grp*8 + ch; 8 edge
// slots per wave, lane gathers 16 B (= 8 bf16) of x[col]. fp32 accumulate.
// 4-deep unrolled main loop + 2-edge + 1-edge remainder (at the ~3.5 TB/s
// random-gather service-rate equilibrium -- do not touch).
// 1/16384 val-scale hoisted to the per-row epilogue. shfl_xor(8,16,32).
// Defer-acc: MID layers write ONLY y. LAST reconstructs
// acc = 0.25*(emb0_bf16 + y1 + y2 + s3); y2 == this layer's x buffer.
// ===========================================================================
template <bool LAST>
__global__ void k_spmm_bf(const int2* __restrict__ rowptr2,
                          const unsigned* __restrict__ ecv,
                          const uint4* __restrict__ x, uint4* __restrict__ y,
                          float* __restrict__ acc,
                          const uint4* __restrict__ e0b,
                          const uint4* __restrict__ y1,
                          int N) {
    int wid = (blockIdx.x * blockDim.x + threadIdx.x) >> 6;
    if (wid >= N) return;
    int lane = threadIdx.x & 63;
    int grp  = lane >> 3;          // edge slot within wave [0,8)
    unsigned ch = (unsigned)(lane & 7);   // 16B chunk of the 128B bf16 row
    int2 rp = rowptr2[wid];
    int e0 = rp.x;
    int e1 = rp.y;
    float s0 = 0.f, s1 = 0.f, s2 = 0.f, s3 = 0.f;
    float s4 = 0.f, s5 = 0.f, s6 = 0.f, s7 = 0.f;
    int e = e0 + grp;
    // ---- 4-deep main loop: 4 outstanding gathers per lane ----
    for (; e + 24 < e1; e += 32) {
        unsigned A0 = ecv[e];
        unsigned A1 = ecv[e + 8];
        unsigned A2 = ecv[e + 16];
        unsigned A3 = ecv[e + 24];
        uint4 x0 = x[((A0 >> 11) & ~7u) | ch];
        uint4 x1 = x[((A1 >> 11) & ~7u) | ch];
        uint4 x2 = x[((A2 >> 11) & ~7u) | ch];
        uint4 x3 = x[((A3 >> 11) & ~7u) | ch];
        float v0 = (float)(A0 & 0x3FFFu);
        float v1 = (float)(A1 & 0x3FFFu);
        float v2 = (float)(A2 & 0x3FFFu);
        float v3 = (float)(A3 & 0x3FFFu);
        s0 += v0 * blo(x0.x) + v1 * blo(x1.x) + v2 * blo(x2.x) + v3 * blo(x3.x);
        s1 += v0 * bhi(x0.x) + v1 * bhi(x1.x) + v2 * bhi(x2.x) + v3 * bhi(x3.x);
        s2 += v0 * blo(x0.y) + v1 * blo(x1.y) + v2 * blo(x2.y) + v3 * blo(x3.y);
        s3 += v0 * bhi(x0.y) + v1 * bhi(x1.y) + v2 * bhi(x2.y) + v3 * bhi(x3.y);
        s4 += v0 * blo(x0.z) + v1 * blo(x1.z) + v2 * blo(x2.z) + v3 * blo(x3.z);
        s5 += v0 * bhi(x0.z) + v1 * bhi(x1.z) + v2 * bhi(x2.z) + v3 * bhi(x3.z);
        s6 += v0 * blo(x0.w) + v1 * blo(x1.w) + v2 * blo(x2.w) + v3 * blo(x3.w);
        s7 += v0 * bhi(x0.w) + v1 * bhi(x1.w) + v2 * bhi(x2.w) + v3 * bhi(x3.w);
    }
    // ---- 2-edge step ----
    for (; e + 8 < e1; e += 16) {
        unsigned A = ecv[e];
        unsigned C = ecv[e + 8];
        uint4 xa = x[((A >> 11) & ~7u) | ch];
        uint4 xc = x[((C >> 11) & ~7u) | ch];
        float va = (float)(A & 0x3FFFu);
        float vc = (float)(C & 0x3FFFu);
        s0 += va * blo(xa.x) + vc * blo(xc.x);
        s1 += va * bhi(xa.x) + vc * bhi(xc.x);
        s2 += va * blo(xa.y) + vc * blo(xc.y);
        s3 += va * bhi(xa.y) + vc * bhi(xc.y);
        s4 += va * blo(xa.z) + vc * blo(xc.z);
        s5 += va * bhi(xa.z) + vc * bhi(xc.z);
        s6 += va * blo(xa.w) + vc * blo(xc.w);
        s7 += va * bhi(xa.w) + vc * bhi(xc.w);
    }
    if (e < e1) {
        unsigned A = ecv[e];
        uint4 xa = x[((A >> 11) & ~7u) | ch];
        float va = (float)(A & 0x3FFFu);
        s0 += va * blo(xa.x); s1 += va * bhi(xa.x);
        s2 += va * blo(xa.y); s3 += va * bhi(xa.y);
        s4 += va * blo(xa.z); s5 += va * bhi(xa.z);
        s6 += va * blo(xa.w); s7 += va * bhi(xa.w);
    }
    #pragma unroll
    for (int m = 8; m <= 32; m <<= 1) {
        s0 += __shfl_xor(s0, m); s1 += __shfl_xor(s1, m);
        s2 += __shfl_xor(s2, m); s3 += __shfl_xor(s3, m);
        s4 += __shfl_xor(s4, m); s5 += __shfl_xor(s5, m);
        s6 += __shfl_xor(s6, m); s7 += __shfl_xor(s7, m);
    }
    if (grp == 0) {
        if (!LAST) {
            // mid layer: write y only -- zero acc traffic
            const float SC = 1.f / 16384.f;
            y[(size_t)wid * 8 + ch] =
                make_uint4(pack_bf2(s0 * SC, s1 * SC), pack_bf2(s2 * SC, s3 * SC),
                           pack_bf2(s4 * SC, s5 * SC), pack_bf2(s6 * SC, s7 * SC));
        } else {
            // final merge: acc = 0.25*(emb0 + y1 + y2) + s*0.25/16384
            const float SC25 = 0.25f / 16384.f;
            size_t ro = (size_t)wid * 8 + ch;
            uint4 u0 = e0b[ro];
            uint4 u1 = y1[ro];
            uint4 u2 = x [ro];
            float4 a0, a1;
            a0.x = (blo(u0.x) + blo(u1.x) + blo(u2.x)) * 0.25f + s0 * SC25;
            a0.y = (bhi(u0.x) + bhi(u1.x) + bhi(u2.x)) * 0.25f + s1 * SC25;
            a0.z = (blo(u0.y) + blo(u1.y) + blo(u2.y)) * 0.25f + s2 * SC25;
            a0.w = (bhi(u0.y) + bhi(u1.y) + bhi(u2.y)) * 0.25f + s3 * SC25;
            a1.x = (blo(u0.z) + blo(u1.z) + blo(u2.z)) * 0.25f + s4 * SC25;
            a1.y = (bhi(u0.z) + bhi(u1.z) + bhi(u2.z)) * 0.25f + s5 * SC25;
            a1.z = (blo(u0.w) + blo(u1.w) + blo(u2.w)) * 0.25f + s6 * SC25;
            a1.w = (bhi(u0.w) + bhi(u1.w) + bhi(u2.w)) * 0.25f + s7 * SC25;
            size_t o = ((size_t)wid << 6) + (ch << 3);
            *(float4*)(acc + o)     = a0;
            *(float4*)(acc + o + 4) = a1;
        }
    }
}

// ===========================================================================
// Fallback (atomic path, fp32) if ws is too small
// ===========================================================================
__global__ void k_init(const float4* __restrict__ ue, const float4* __restrict__ ie,
                       float4* __restrict__ cur, float4* __restrict__ acc,
                       int nUser4, int nTot4) {
    int stride = gridDim.x * blockDim.x;
    for (int i = blockIdx.x * blockDim.x + threadIdx.x; i < nTot4; i += stride) {
        float4 v = (i < nUser4) ? ue[i] : ie[i - nUser4];
        cur[i] = v;
        acc[i] = v;
    }
}

__global__ void k_spmm_atomic(const int* __restrict__ row, const int* __restrict__ col,
                              const float* __restrict__ val, const float* __restrict__ x,
                              float* __restrict__ y, int nnz) {
    long long total  = (long long)nnz * 16;
    long long stride = (long long)gridDim.x * blockDim.x;
    for (long long idx = (long long)blockIdx.x * blockDim.x + threadIdx.x;
         idx < total; idx += stride) {
        int e = (int)(idx >> 4);
        int c = (int)(idx & 15);
        int r = row[e];
        int ssrc = col[e];
        float v = val[e];
        float4 xv = *(const float4*)(x + (size_t)ssrc * D + c * 4);
        float* yp = y + (size_t)r * D + c * 4;
        atomicAdd(yp + 0, v * xv.x);
        atomicAdd(yp + 1, v * xv.y);
        atomicAdd(yp + 2, v * xv.z);
        atomicAdd(yp + 3, v * xv.w);
    }
}

__global__ void k_acc(const float4* __restrict__ nxt, float4* __restrict__ acc,
                      float scale, int n4) {
    int stride = gridDim.x * blockDim.x;
    for (int i = blockIdx.x * blockDim.x + threadIdx.x; i < n4; i += stride) {
        float4 a = acc[i];
        float4 b = nxt[i];
        a.x = (a.x + b.x) * scale;
        a.y = (a.y + b.y) * scale;
        a.z = (a.z + b.z) * scale;
        a.w = (a.w + b.w) * scale;
        acc[i] = a;
    }
}

// ===========================================================================
extern "C" void kernel_launch(void* const* d_in, const int* in_sizes, int n_in,
                              void* d_out, int out_size, void* d_ws, size_t ws_size,
                              hipStream_t stream) {
    const float* ue  = (const float*)d_in[0];
    const float* ie  = (const float*)d_in[1];
    const int*   row = (const int*)  d_in[2];
    const int*   col = (const int*)  d_in[3];
    const float* val = (const float*)d_in[4];

    const int n_users = in_sizes[0] / D;
    const int n_items = in_sizes[1] / D;
    const int nnz     = in_sizes[2];
    const int N       = n_users + n_items;
    const int NB2     = (N + (1 << SH2) - 1) >> SH2;   // 586

    float* acc = (float*)d_out;
    const size_t bf16B = (size_t)N * D * 2;    // 19.2 MB per layer buffer
    auto aup = [](size_t x) { return (x + 255) & ~(size_t)255; };

    size_t off = 0;
    uint4* buf0 = (uint4*)((char*)d_ws + off); off += aup(bf16B);   // emb0 bf16
    uint4* buf1 = (uint4*)((char*)d_ws + off); off += aup(bf16B);   // y1
    uint4* buf2 = (uint4*)((char*)d_ws + off); off += aup(bf16B);   // y2
    unsigned*      g1 = (unsigned*)     ((char*)d_ws + off); off += aup((size_t)NB2 * CAP * 4);
    unsigned char* lr = (unsigned char*)((char*)d_ws + off); off += aup((size_t)NB2 * CAP);
    unsigned*      ecv = (unsigned*)    ((char*)d_ws + off); off += aup((size_t)NB2 * CAP * 4);
    int2* rowptr2 = (int2*)((char*)d_ws + off); off += aup((size_t)(NB2 << SH2) * 8);
    int*  gcnt    = (int*) ((char*)d_ws + off); off += aup((size_t)NB2 * 4);
    const size_t needCSR = off;                 // ~106 MB (< ~117 MB proven in round-0)

    // capacity guard: mean bucket load + ~6.6 sigma must fit in CAP;
    // col must fit 18 bits for the (col<<14) packing
    bool capOK = ((size_t)nnz / NB2 + 600) <= (size_t)CAP && NB2 <= 768 &&
                 N <= (1 << 18);

    if (ws_size >= needCSR && capOK) {
        // ---- single-pass radix partition (fixed-CAP buckets) + fused init ----
        hipMemsetAsync(gcnt, 0, (size_t)NB2 * 4, stream);
        int nTiles = (nnz + T1 - 1) / T1;      // 1172
        int nInit  = NINIT < nTiles ? NINIT : nTiles;
        int nTot8  = N * 8;
        int nUser8 = n_users * 8;
        k_part1f<<<nTiles + nInit, 256, 0, stream>>>(row, col, val, gcnt, g1, lr,
                                                     nnz, NB2, nInit,
                                                     (const float4*)ue, (const float4*)ie,
                                                     buf0, nUser8, nTot8);
        k_part2<<<NB2, 512, 0, stream>>>(gcnt, g1, lr, ecv, rowptr2);

        // ---- 3 SpMM layers, defer-acc:
        //   L1: y1 = A*x0      (buf0 -> buf1), no acc traffic
        //   L2: y2 = A*y1      (buf1 -> buf2), no acc traffic
        //   L3: acc = 0.25*(emb0 + y1 + y2 + A*y2)
        int grid = (N + 3) / 4;   // one wave per row
        k_spmm_bf<false><<<grid, 256, 0, stream>>>(rowptr2, ecv, buf0, buf1,
                                                   nullptr, nullptr, nullptr, N);
        k_spmm_bf<false><<<grid, 256, 0, stream>>>(rowptr2, ecv, buf1, buf2,
                                                   nullptr, nullptr, nullptr, N);
        k_spmm_bf<true ><<<grid, 256, 0, stream>>>(rowptr2, ecv, buf2, nullptr,
                                                   acc, buf0, buf1, N);
    } else {
        // ---- fallback: atomic scatter path (fp32) ----
        const size_t denseB = (size_t)N * D * sizeof(float);
        float* fa = (float*)d_ws;
        float* fb = fa + (size_t)N * D;
        const int nTot4  = N * D / 4;
        const int nUser4 = n_users * D / 4;
        k_init<<<2048, 256, 0, stream>>>((const float4*)ue, (const float4*)ie,
                                         (float4*)fa, (float4*)acc, nUser4, nTot4);
        float* curp = fa;
        float* nxt  = fb;
        for (int l = 0; l < N_LAYERS; ++l) {
            hipMemsetAsync(nxt, 0, denseB, stream);
            k_spmm_atomic<<<8192, 256, 0, stream>>>(row, col, val, curp, nxt, nnz);
            float scale = (l == N_LAYERS - 1) ? (1.0f / (N_LAYERS + 1)) : 1.0f;
            k_acc<<<2048, 256, 0, stream>>>((const float4*)nxt, (float4*)acc, scale, nTot4);
            float* t = curp; curp = nxt; nxt = t;
        }
    }
}